// Round 1
// baseline (311.061 us; speedup 1.0000x reference)
//
#include <hip/hip_runtime.h>
#include <hip/hip_bf16.h>
#include <cstdint>
#include <cstddef>

// ---------------- types ----------------
typedef __attribute__((ext_vector_type(8))) short     bf16x8;
typedef __attribute__((ext_vector_type(4))) float     f32x4;
typedef __attribute__((ext_vector_type(4))) unsigned short u16x4;

using as1_void = __attribute__((address_space(1))) void;
using as3_void = __attribute__((address_space(3))) void;

#define MFMA16(a,b,c) __builtin_amdgcn_mfma_f32_16x16x32_bf16((a),(b),(c),0,0,0)

__device__ __forceinline__ unsigned short f2bf(float f) {
  union { float f; unsigned u; } v; v.f = f;
  unsigned r = v.u + 0x7fffu + ((v.u >> 16) & 1u);
  return (unsigned short)(r >> 16);
}

__device__ __forceinline__ void gload16(const void* g, void* l) {
  __builtin_amdgcn_global_load_lds((const as1_void*)g, (as3_void*)l, 16, 0, 0);
}

// ---------------- problem constants ----------------
// B=2, U1=U2=3072, IF=256, FD=256, M=4, D=64
// ws layout (byte offsets)
constexpr size_t oXq  = 0;                       // bf16 [2*3072*256]
constexpr size_t oXk  = oXq + 1572864ull * 2;    // bf16 [2*3072*256]
constexpr size_t oWq  = oXk + 1572864ull * 2;    // bf16 [256*256]
constexpr size_t oWv  = oWq + 65536ull   * 2;    // bf16 [1024*256]
constexpr size_t oWm  = oWv + 262144ull  * 2;    // bf16 [256*256]
constexpr size_t oWo  = oWm + 65536ull   * 2;    // bf16 [256*256]
constexpr size_t oQb  = oWo + 65536ull   * 2;    // bf16 [8][3072][64]  (q/8)
constexpr size_t oKb  = oQb + 1572864ull * 2;    // bf16 [8][3072][64]
constexpr size_t oVb  = oKb + 1572864ull * 2;    // bf16 [8][256][3072] (V^T)
constexpr size_t oFu  = oVb + 6291456ull * 2;    // f32  [8][3072][256] fused
constexpr size_t oOut = oFu + 6291456ull * 4;    // f32  [8][3072][256] outp
constexpr size_t oSc  = oOut + 6291456ull * 4;   // f32  [8][3072] mode scores

// ================= kernel 1: f32 -> bf16 conversion of inputs =================
__global__ __launch_bounds__(256) void cvt_kernel(
    const float* __restrict__ q, const float* __restrict__ k,
    const float* __restrict__ wq, const float* __restrict__ wv,
    const float* __restrict__ wm, const float* __restrict__ wo,
    unsigned short* __restrict__ ws) {
  int i4 = (blockIdx.x * 256 + threadIdx.x) * 4;
  const float* src; int local;
  if (i4 < 1572864)       { src = q;  local = i4; }
  else if (i4 < 3145728)  { src = k;  local = i4 - 1572864; }
  else if (i4 < 3211264)  { src = wq; local = i4 - 3145728; }
  else if (i4 < 3473408)  { src = wv; local = i4 - 3211264; }
  else if (i4 < 3538944)  { src = wm; local = i4 - 3473408; }
  else                    { src = wo; local = i4 - 3538944; }
  f32x4 v = *(const f32x4*)(src + local);
  u16x4 o;
  o.x = f2bf(v.x); o.y = f2bf(v.y); o.z = f2bf(v.z); o.w = f2bf(v.w);
  *(u16x4*)(ws + i4) = o;   // dst offset == concat offset (segments mirror inputs)
}

// ================= kernel 2: projections q,k,v =================
// grid 2304: rowblk = bid%384 (16 rows of 6144 = b*3072+u), ny = bid/384:
//   ny=0: q = Xq@Wq^T * 0.125 -> qb[bm][u][64]
//   ny=1: k = Xk@Wq^T         -> kb[bm][u][64]
//   ny=2..5: v chunk = Xk@Wv^T + bv -> vbT[bm][f][u] (transposed)
__global__ __launch_bounds__(256) void proj_kernel(const float* __restrict__ bv,
                                                   char* __restrict__ wsb) {
  int lane = threadIdx.x & 63, wid = threadIdx.x >> 6;
  int rowblk = blockIdx.x % 384;
  int ny = blockIdx.x / 384;
  int r0 = rowblk * 16;

  const unsigned short* X = (const unsigned short*)(wsb + (ny == 0 ? oXq : oXk));
  const unsigned short* W;
  if (ny <= 1) W = (const unsigned short*)(wsb + oWq);
  else         W = (const unsigned short*)(wsb + oWv) + (size_t)(ny - 2) * 256 * 256;

  int arow = r0 + (lane & 15);
  const unsigned short* Xp = X + (size_t)arow * 256 + ((lane >> 4) * 8);
  int n0 = wid * 64;

  f32x4 acc[4];
#pragma unroll
  for (int bt = 0; bt < 4; ++bt) acc[bt] = (f32x4){0.f, 0.f, 0.f, 0.f};

#pragma unroll
  for (int ks = 0; ks < 8; ++ks) {
    bf16x8 af = *(const bf16x8*)(Xp + ks * 32);
#pragma unroll
    for (int bt = 0; bt < 4; ++bt) {
      int n = n0 + bt * 16 + (lane & 15);
      bf16x8 bf = *(const bf16x8*)(W + (size_t)n * 256 + ks * 32 + ((lane >> 4) * 8));
      acc[bt] = MFMA16(af, bf, acc[bt]);
    }
  }

  int b = r0 / 3072, u0 = r0 % 3072;
  int ubase = u0 + ((lane >> 4) * 4);

  if (ny <= 1) {
    unsigned short* outp = (unsigned short*)(wsb + (ny == 0 ? oQb : oKb));
    float scale = (ny == 0) ? 0.125f : 1.0f;
    int m = wid;  // n0=wid*64 -> m = n>>6 = wid, d = bt*16+(lane&15)
#pragma unroll
    for (int bt = 0; bt < 4; ++bt) {
      int d = bt * 16 + (lane & 15);
#pragma unroll
      for (int r = 0; r < 4; ++r) {
        outp[((size_t)(b * 4 + m) * 3072 + (ubase + r)) * 64 + d] = f2bf(acc[bt][r] * scale);
      }
    }
  } else {
    unsigned short* vbT = (unsigned short*)(wsb + oVb);
    int mchunk = ny - 2;
#pragma unroll
    for (int bt = 0; bt < 4; ++bt) {
      int f = n0 + bt * 16 + (lane & 15);
      float bias = bv[mchunk * 256 + f];
      u16x4 pk;
#pragma unroll
      for (int r = 0; r < 4; ++r) pk[r] = f2bf(acc[bt][r] + bias);
      *(u16x4*)(vbT + ((size_t)(b * 4 + mchunk) * 256 + f) * 3072 + ubase) = pk;
    }
  }
}

// ================= kernel 3: flash attention =================
// grid 768: bm = bid&7 (XCD-resident K/V), qt = bid>>3 (32 q-rows).
// 4 waves: w0/w1 do QK^T + online softmax for rows 0-15/16-31;
// all waves do PV on f-quarter wid*64. K/V staged with XOR chunk swizzle
// (swizzled GLOBAL source + linear LDS dest, swizzled reads).
__global__ __launch_bounds__(256) void attn_kernel(char* __restrict__ wsb) {
  __shared__ unsigned short sK[64 * 64];    // [kv][d]   (chunk-swizzled)
  __shared__ unsigned short sV[256 * 64];   // [f][kv]   (chunk-swizzled)
  __shared__ unsigned short sP[32 * 64];    // [q][kv]   (chunk-swizzled)
  __shared__ float sCorr[32];
  __shared__ float sInv[32];

  int lane = threadIdx.x & 63, wid = threadIdx.x >> 6;
  int bm = blockIdx.x & 7, qt = blockIdx.x >> 3;
  int q0 = qt * 32;

  const unsigned short* qb = (const unsigned short*)(wsb + oQb) + (size_t)bm * 3072 * 64;
  const unsigned short* kb = (const unsigned short*)(wsb + oKb) + (size_t)bm * 3072 * 64;
  const unsigned short* vb = (const unsigned short*)(wsb + oVb) + (size_t)bm * 256 * 3072;
  float* fused = (float*)(wsb + oFu) + (size_t)bm * 3072 * 256;

  bf16x8 qf0 = {}, qf1 = {};
  float mrow[4] = {-1e30f, -1e30f, -1e30f, -1e30f};
  float lrow[4] = {0.f, 0.f, 0.f, 0.f};
  if (wid < 2) {
    int qrow = q0 + wid * 16 + (lane & 15);
    const unsigned short* qp = qb + (size_t)qrow * 64 + ((lane >> 4) * 8);
    qf0 = *(const bf16x8*)(qp);
    qf1 = *(const bf16x8*)(qp + 32);
  }

  f32x4 acc[2][4];
#pragma unroll
  for (int rf = 0; rf < 2; ++rf)
#pragma unroll
    for (int ft = 0; ft < 4; ++ft) acc[rf][ft] = (f32x4){0.f, 0.f, 0.f, 0.f};

  int lr3 = lane >> 3, lc3 = lane & 7;

  for (int kt = 0; kt < 48; ++kt) {
    int kv0 = kt * 64;
    // ---- stage K tile (8 x 1KB chunks) ----
#pragma unroll
    for (int i = 0; i < 2; ++i) {
      int ch = wid * 2 + i;
      int r = ch * 8 + lr3;
      int cs = lc3 ^ (r & 7);
      gload16(kb + (size_t)(kv0 + r) * 64 + cs * 8, &sK[ch * 512]);
    }
    // ---- stage V^T tile (32 x 1KB chunks) ----
#pragma unroll
    for (int i = 0; i < 8; ++i) {
      int ch = i * 4 + wid;
      int f = ch * 8 + lr3;
      int cs = lc3 ^ (f & 7);
      gload16(vb + (size_t)f * 3072 + kv0 + cs * 8, &sV[ch * 512]);
    }
    __syncthreads();   // drains vmcnt -> staging complete

    if (wid < 2) {
      f32x4 s[4];
#pragma unroll
      for (int t = 0; t < 4; ++t) {
        int kvl = t * 16 + (lane & 15);
        int base = kvl * 64;
        bf16x8 k0 = *(const bf16x8*)&sK[base + (((lane >> 4)) ^ (kvl & 7)) * 8];
        bf16x8 k1 = *(const bf16x8*)&sK[base + (((lane >> 4) + 4) ^ (kvl & 7)) * 8];
        f32x4 z = (f32x4){0.f, 0.f, 0.f, 0.f};
        z = MFMA16(qf0, k0, z);
        z = MFMA16(qf1, k1, z);
        s[t] = z;
      }
      int qrl = wid * 16 + ((lane >> 4) * 4);
      float cr[4];
#pragma unroll
      for (int r = 0; r < 4; ++r) {
        float mx = fmaxf(fmaxf(s[0][r], s[1][r]), fmaxf(s[2][r], s[3][r]));
        mx = fmaxf(mx, __shfl_xor(mx, 1));
        mx = fmaxf(mx, __shfl_xor(mx, 2));
        mx = fmaxf(mx, __shfl_xor(mx, 4));
        mx = fmaxf(mx, __shfl_xor(mx, 8));
        float mnew = fmaxf(mrow[r], mx);
        cr[r] = __expf(mrow[r] - mnew);
        mrow[r] = mnew;
        float sum = 0.f;
#pragma unroll
        for (int t = 0; t < 4; ++t) { float p = __expf(s[t][r] - mnew); s[t][r] = p; sum += p; }
        sum += __shfl_xor(sum, 1);
        sum += __shfl_xor(sum, 2);
        sum += __shfl_xor(sum, 4);
        sum += __shfl_xor(sum, 8);
        lrow[r] = lrow[r] * cr[r] + sum;
      }
#pragma unroll
      for (int t = 0; t < 4; ++t) {
        int kv = t * 16 + (lane & 15);
#pragma unroll
        for (int r = 0; r < 4; ++r) {
          int qq = qrl + r;
          sP[qq * 64 + (((kv >> 3) ^ (qq & 7)) << 3) + (kv & 7)] = f2bf(s[t][r]);
        }
      }
      if ((lane & 15) == 0) {
#pragma unroll
        for (int r = 0; r < 4; ++r) sCorr[qrl + r] = cr[r];
      }
    }
    __syncthreads();

    // ---- all waves: rescale + PV ----
    float c[2][4];
#pragma unroll
    for (int rf = 0; rf < 2; ++rf)
#pragma unroll
      for (int r = 0; r < 4; ++r) c[rf][r] = sCorr[rf * 16 + ((lane >> 4) * 4) + r];
#pragma unroll
    for (int rf = 0; rf < 2; ++rf)
#pragma unroll
      for (int ft = 0; ft < 4; ++ft)
#pragma unroll
        for (int r = 0; r < 4; ++r) acc[rf][ft][r] *= c[rf][r];

    bf16x8 pa[2][2];
#pragma unroll
    for (int rf = 0; rf < 2; ++rf)
#pragma unroll
      for (int t2 = 0; t2 < 2; ++t2) {
        int qq = rf * 16 + (lane & 15);
        pa[rf][t2] = *(const bf16x8*)&sP[qq * 64 + (((t2 * 4 + (lane >> 4)) ^ (qq & 7)) << 3)];
      }
#pragma unroll
    for (int ft = 0; ft < 4; ++ft) {
      int f = wid * 64 + ft * 16 + (lane & 15);
#pragma unroll
      for (int t2 = 0; t2 < 2; ++t2) {
        bf16x8 vf = *(const bf16x8*)&sV[f * 64 + (((t2 * 4 + (lane >> 4)) ^ (f & 7)) << 3)];
        acc[0][ft] = MFMA16(pa[0][t2], vf, acc[0][ft]);
        acc[1][ft] = MFMA16(pa[1][t2], vf, acc[1][ft]);
      }
    }
    __syncthreads();   // protect sK/sV/sP/sCorr before next stage
  }

  if (wid < 2 && (lane & 15) == 0) {
    int qrl = wid * 16 + ((lane >> 4) * 4);
#pragma unroll
    for (int r = 0; r < 4; ++r) sInv[qrl + r] = 1.0f / lrow[r];
  }
  __syncthreads();

#pragma unroll
  for (int rf = 0; rf < 2; ++rf) {
    int row = rf * 16 + ((lane >> 4) * 4);
#pragma unroll
    for (int ft = 0; ft < 4; ++ft) {
      int col = wid * 64 + ft * 16 + (lane & 15);
#pragma unroll
      for (int r = 0; r < 4; ++r) {
        fused[(size_t)(q0 + row + r) * 256 + col] = acc[rf][ft][r] * sInv[row + r];
      }
    }
  }
}

// ================= kernel 4: FFN + LN + agg scores =================
// 16 bmu-rows per block (grid 1536); wave w owns cols w*64..w*64+63.
__global__ __launch_bounds__(256) void ffn_kernel(char* __restrict__ wsb,
                                                  const float* __restrict__ bmid,
                                                  const float* __restrict__ bout,
                                                  const float* __restrict__ lng,
                                                  const float* __restrict__ lnb,
                                                  const float* __restrict__ wagg,
                                                  const float* __restrict__ bagg) {
  __shared__ unsigned short sA[16 * 256];  // fused bf16 (chunk-swizzled)
  __shared__ unsigned short sM[16 * 256];  // mid   bf16 (chunk-swizzled)
  __shared__ float redS[4][16], redQ[4][16], redC[4][16];

  int lane = threadIdx.x & 63, wid = threadIdx.x >> 6;
  int r0 = blockIdx.x * 16;

  const float* fused = (const float*)(wsb + oFu);
  float* outp = (float*)(wsb + oOut);
  float* scores = (float*)(wsb + oSc);
  const unsigned short* Wm = (const unsigned short*)(wsb + oWm);
  const unsigned short* Wo = (const unsigned short*)(wsb + oWo);

  // ---- load fused rows -> sA (bf16, swizzled) ----
  {
    int t = threadIdx.x;
    const float* src = fused + (size_t)r0 * 256 + t * 16;
    int row = (t * 16) >> 8;
    int k0 = (t * 16) & 255;
    f32x4 v0 = *(const f32x4*)(src);
    f32x4 v1 = *(const f32x4*)(src + 4);
    f32x4 v2 = *(const f32x4*)(src + 8);
    f32x4 v3 = *(const f32x4*)(src + 12);
    int cA = k0 >> 3;
    unsigned short* pA = &sA[row * 256 + ((cA ^ (row & 7)) << 3)];
    unsigned short* pB = &sA[row * 256 + (((cA + 1) ^ (row & 7)) << 3)];
    pA[0] = f2bf(v0.x); pA[1] = f2bf(v0.y); pA[2] = f2bf(v0.z); pA[3] = f2bf(v0.w);
    pA[4] = f2bf(v1.x); pA[5] = f2bf(v1.y); pA[6] = f2bf(v1.z); pA[7] = f2bf(v1.w);
    pB[0] = f2bf(v2.x); pB[1] = f2bf(v2.y); pB[2] = f2bf(v2.z); pB[3] = f2bf(v2.w);
    pB[4] = f2bf(v3.x); pB[5] = f2bf(v3.y); pB[6] = f2bf(v3.z); pB[7] = f2bf(v3.w);
  }
  __syncthreads();

  int n0 = wid * 64;
  int rowb = (lane >> 4) * 4;

  // ---- GEMM1: fused @ Wm^T ----
  f32x4 acc1[4];
#pragma unroll
  for (int bt = 0; bt < 4; ++bt) acc1[bt] = (f32x4){0.f, 0.f, 0.f, 0.f};
#pragma unroll
  for (int ks = 0; ks < 8; ++ks) {
    int row = lane & 15;
    bf16x8 af = *(const bf16x8*)&sA[row * 256 + (((ks * 4 + (lane >> 4)) ^ (row & 7)) << 3)];
#pragma unroll
    for (int bt = 0; bt < 4; ++bt) {
      int n = n0 + bt * 16 + (lane & 15);
      bf16x8 bf = *(const bf16x8*)(Wm + (size_t)n * 256 + ks * 32 + ((lane >> 4) * 8));
      acc1[bt] = MFMA16(af, bf, acc1[bt]);
    }
  }
  // gelu (exact) -> sM
#pragma unroll
  for (int bt = 0; bt < 4; ++bt) {
    int n = n0 + bt * 16 + (lane & 15);
    float bb = bmid[n];
#pragma unroll
    for (int r = 0; r < 4; ++r) {
      float x = acc1[bt][r] + bb;
      float g = 0.5f * x * (1.0f + erff(x * 0.7071067811865475f));
      int row = rowb + r;
      sM[row * 256 + (((n >> 3) ^ (row & 7)) << 3) + (n & 7)] = f2bf(g);
    }
  }
  __syncthreads();

  // ---- GEMM2: mid @ Wo^T ----
  f32x4 acc2[4];
#pragma unroll
  for (int bt = 0; bt < 4; ++bt) acc2[bt] = (f32x4){0.f, 0.f, 0.f, 0.f};
#pragma unroll
  for (int ks = 0; ks < 8; ++ks) {
    int row = lane & 15;
    bf16x8 af = *(const bf16x8*)&sM[row * 256 + (((ks * 4 + (lane >> 4)) ^ (row & 7)) << 3)];
#pragma unroll
    for (int bt = 0; bt < 4; ++bt) {
      int n = n0 + bt * 16 + (lane & 15);
      bf16x8 bf = *(const bf16x8*)(Wo + (size_t)n * 256 + ks * 32 + ((lane >> 4) * 8));
      acc2[bt] = MFMA16(af, bf, acc2[bt]);
    }
  }

  // ---- + b_out + residual; LN partials ----
  float xv[4][4];
  float sS[4] = {0.f, 0.f, 0.f, 0.f}, sQ[4] = {0.f, 0.f, 0.f, 0.f};
#pragma unroll
  for (int bt = 0; bt < 4; ++bt) {
    int n = n0 + bt * 16 + (lane & 15);
    float bo = bout[n];
#pragma unroll
    for (int r = 0; r < 4; ++r) {
      float x = acc2[bt][r] + bo + fused[(size_t)(r0 + rowb + r) * 256 + n];
      xv[bt][r] = x;
      sS[r] += x;
      sQ[r] += x * x;
    }
  }
#pragma unroll
  for (int r = 0; r < 4; ++r) {
#pragma unroll
    for (int off = 1; off < 16; off <<= 1) {
      sS[r] += __shfl_xor(sS[r], off);
      sQ[r] += __shfl_xor(sQ[r], off);
    }
  }
  if ((lane & 15) == 0) {
#pragma unroll
    for (int r = 0; r < 4; ++r) { redS[wid][rowb + r] = sS[r]; redQ[wid][rowb + r] = sQ[r]; }
  }
  __syncthreads();

  float scp[4] = {0.f, 0.f, 0.f, 0.f};
#pragma unroll
  for (int r = 0; r < 4; ++r) {
    int row = rowb + r;
    float ts = redS[0][row] + redS[1][row] + redS[2][row] + redS[3][row];
    float tq = redQ[0][row] + redQ[1][row] + redQ[2][row] + redQ[3][row];
    float mean = ts * (1.0f / 256.0f);
    float var = tq * (1.0f / 256.0f) - mean * mean;
    float rs = rsqrtf(var + 1e-12f);
#pragma unroll
    for (int bt = 0; bt < 4; ++bt) {
      int n = n0 + bt * 16 + (lane & 15);
      float o = (xv[bt][r] - mean) * rs * lng[n] + lnb[n];
      outp[(size_t)(r0 + row) * 256 + n] = o;
      scp[r] += o * wagg[n];
    }
  }
#pragma unroll
  for (int r = 0; r < 4; ++r) {
#pragma unroll
    for (int off = 1; off < 16; off <<= 1) scp[r] += __shfl_xor(scp[r], off);
  }
  if ((lane & 15) == 0) {
#pragma unroll
    for (int r = 0; r < 4; ++r) redC[wid][rowb + r] = scp[r];
  }
  __syncthreads();
  if (wid == 0 && lane < 16) {
    scores[r0 + lane] = redC[0][lane] + redC[1][lane] + redC[2][lane] + redC[3][lane] + bagg[0];
  }
}

// ================= kernel 5: mode-softmax aggregation =================
__global__ __launch_bounds__(256) void agg_kernel(const char* __restrict__ wsb,
                                                  float* __restrict__ out) {
  int gid = blockIdx.x * 256 + threadIdx.x;
  int bu = gid >> 6;            // 0..6143  (= b*3072+u)
  int f0 = (gid & 63) * 4;
  int b = bu / 3072, u = bu % 3072;
  const float* scores = (const float*)(wsb + oSc);
  const float* outp = (const float*)(wsb + oOut);

  float sc[4];
#pragma unroll
  for (int m = 0; m < 4; ++m) sc[m] = scores[(size_t)(b * 4 + m) * 3072 + u];
  float mx = fmaxf(fmaxf(sc[0], sc[1]), fmaxf(sc[2], sc[3]));
  float e[4]; float sum = 0.f;
#pragma unroll
  for (int m = 0; m < 4; ++m) { e[m] = __expf(sc[m] - mx); sum += e[m]; }
  float inv = 1.0f / sum;

  f32x4 o = (f32x4){0.f, 0.f, 0.f, 0.f};
#pragma unroll
  for (int m = 0; m < 4; ++m) {
    f32x4 v = *(const f32x4*)(outp + ((size_t)(b * 4 + m) * 3072 + u) * 256 + f0);
    float w = e[m] * inv;
    o.x += v.x * w; o.y += v.y * w; o.z += v.z * w; o.w += v.w * w;
  }
  *(f32x4*)(out + (size_t)bu * 256 + f0) = o;
}

// ================= launcher =================
extern "C" void kernel_launch(void* const* d_in, const int* in_sizes, int n_in,
                              void* d_out, int out_size, void* d_ws, size_t ws_size,
                              hipStream_t stream) {
  const float* q  = (const float*)d_in[0];
  const float* k  = (const float*)d_in[1];
  const float* wq = (const float*)d_in[2];
  const float* wv = (const float*)d_in[3];
  const float* bv = (const float*)d_in[4];
  const float* wm = (const float*)d_in[5];
  const float* bm = (const float*)d_in[6];
  const float* wo = (const float*)d_in[7];
  const float* bo = (const float*)d_in[8];
  const float* lg = (const float*)d_in[9];
  const float* lb = (const float*)d_in[10];
  const float* wa = (const float*)d_in[11];
  const float* ba = (const float*)d_in[12];
  char* wsb = (char*)d_ws;

  cvt_kernel<<<3520, 256, 0, stream>>>(q, k, wq, wv, wm, wo, (unsigned short*)wsb);
  proj_kernel<<<2304, 256, 0, stream>>>(bv, wsb);
  attn_kernel<<<768, 256, 0, stream>>>(wsb);
  ffn_kernel<<<1536, 256, 0, stream>>>(wsb, bm, bo, lg, lb, wa, ba);
  agg_kernel<<<1536, 256, 0, stream>>>(wsb, (float*)d_out);
}